// Round 10
// baseline (197.535 us; speedup 1.0000x reference)
//
#include <hip/hip_runtime.h>
#include <hip/hip_bf16.h>
#include <stdint.h>

// W-MSA on flat-reinterpreted windows.
// pp = n1<<10|n3<<6|w2<<3|w4  ->  P = n1<<10|w2<<7|n3<<3|w4
// QKV/proj are plain GEMMs on x.view(B*16384,384) in pp-row order; each
// attention (h,n') block is a contiguous 2048-element chunk of the FLAT
// [pp*384+c] Q/K/V arrays, viewed [64][32] row-major.
// qkv R10: wave-tile 128x64 (acc[8][4]) -> BM=512, BN=128, 8 waves (4Mx2N),
// 3-slot 40KB ring, one barrier/K-step, counted vmcnt(5). Rationale: R9's
// 64x64 tiles gave 6:1 LDS-read:MFMA cycle ratio; 128x64 gives 2.3:1.

typedef __bf16 bf16_t;
typedef __bf16 bf16x8 __attribute__((ext_vector_type(8)));
typedef __bf16 bf16x4 __attribute__((ext_vector_type(4)));
typedef float f32x4 __attribute__((ext_vector_type(4)));

__device__ __forceinline__ void gload_lds16(const void* g, void* l) {
  __builtin_amdgcn_global_load_lds((__attribute__((address_space(1))) void*)(g),
                                   (__attribute__((address_space(3))) void*)(l),
                                   16, 0, 0);
}

// ---------------- weight fp32->bf16 (Wq|Wk|Wv concatenated, then Wp) -------
__global__ __launch_bounds__(256) void convw_kernel(
    const float* __restrict__ wq, const float* __restrict__ wk,
    const float* __restrict__ wv, const float* __restrict__ wp,
    bf16_t* __restrict__ oq, bf16_t* __restrict__ ok,
    bf16_t* __restrict__ ov, bf16_t* __restrict__ op_) {
  int i = blockIdx.x * 256 + threadIdx.x;  // grid covers exactly 147456
  oq[i] = (bf16_t)wq[i];
  ok[i] = (bf16_t)wk[i];
  ov[i] = (bf16_t)wv[i];
  op_[i] = (bf16_t)wp[i];
}

// ---------------- prep: row-permute + cast ----------------
__global__ __launch_bounds__(256) void prep_kernel(const float* __restrict__ x,
                                                   bf16_t* __restrict__ Xp) {
  int gid = blockIdx.x * 256 + threadIdx.x;   // 65536 rows * 96 float4 chunks
  int row = gid / 96;
  int c4 = (gid - row * 96) * 4;
  int b = row >> 14;
  int pp = row & 16383;
  int n1 = pp >> 10, n3 = (pp >> 6) & 15, w2 = (pp >> 3) & 7, w4 = pp & 7;
  int P = (n1 << 10) | (w2 << 7) | (n3 << 3) | w4;
  float4 v = *(const float4*)(x + (size_t)((b << 14) | P) * 384 + c4);
  bf16x4 o;
  o[0] = (bf16_t)v.x; o[1] = (bf16_t)v.y; o[2] = (bf16_t)v.z; o[3] = (bf16_t)v.w;
  *(bf16x4*)(Xp + (size_t)row * 384 + c4) = o;
}

// ---------------- QKV GEMM: 512-row tiles, 128x64 wave tiles ----------
// Slot (kt%3): A [512 rows][4 granules of 16B] 32KB | B [128][4] 8KB.
// Granule g of row r stored at position g^((r>>1)&3) via swizzled SOURCE
// address (linear glds dest); read position hi^((l15>>1)&3) (R2-verified).
__global__ __launch_bounds__(512, 2) void qkv_gemm(
    const bf16_t* __restrict__ Xp, const bf16_t* __restrict__ Wcat,
    const float* __restrict__ bq, const float* __restrict__ bk,
    const float* __restrict__ bv,
    bf16_t* __restrict__ Qs, bf16_t* __restrict__ Ks, bf16_t* __restrict__ Vs) {
  extern __shared__ __align__(16) char smem[];  // 3 * 40960 = 122880 B
  const int tid = threadIdx.x;
  const int F = blockIdx.x;            // 1152 = 8 xcd * 9 j * 16 gq
  const int xcd = F & 7;
  const int t = F >> 3;
  const int j = t % 9;                 // n-tile over 1152 out chans
  const int gq = t / 9;
  const int m0 = (gq * 8 + xcd) * 512; // pixel-row tile (512 rows)
  const int which = j / 3;
  const int cb = (j % 3) * 128;
  const float* bias = which == 0 ? bq : (which == 1 ? bk : bv);
  bf16_t* Out = which == 0 ? Qs : (which == 1 ? Ks : Vs);
  const bf16_t* Arows = Xp + (size_t)m0 * 384;
  const bf16_t* Brows = Wcat + (size_t)j * 128 * 384;

  const int lane = tid & 63, wid = tid >> 6;
  const int l15 = lane & 15, hi = lane >> 4;
  const int wr = wid >> 1, wc = wid & 1;     // 4M x 2N waves
  const int slot = hi ^ ((l15 >> 1) & 3);    // swizzled read position

  auto stage = [&](int kt) {                 // 5 glds/thread
    const int k0 = kt * 32;
    char* base = smem + (kt % 3) * 40960;
#pragma unroll
    for (int jj = 0; jj < 4; ++jj) {         // A: 512 rows x 4 granules
      int idx = jj * 512 + tid;
      int row = idx >> 2;
      int sg = (idx & 3) ^ ((idx >> 3) & 3);
      gload_lds16(Arows + (size_t)row * 384 + k0 + sg * 8,
                  base + (jj * 512 + wid * 64) * 16);
    }
    {                                        // B: 128 rows x 4 granules
      int row = tid >> 2;
      int sg = (tid & 3) ^ ((tid >> 3) & 3);
      gload_lds16(Brows + (size_t)row * 384 + k0 + sg * 8,
                  base + 32768 + (wid * 64) * 16);
    }
  };

  stage(0); stage(1);
  // own tile-0 loads done before the barrier -> barrier publishes tile 0;
  // step 0 reads only slot 0. Tile 1 publishes at step 1's barrier (after
  // end-of-step-0 vmcnt(5)).
  asm volatile("s_waitcnt vmcnt(5)" ::: "memory");
  __builtin_amdgcn_s_barrier();
  __builtin_amdgcn_sched_barrier(0);

  f32x4 acc[8][4] = {};
#pragma unroll
  for (int kt = 0; kt < 12; ++kt) {
    if (kt > 0) {
      __builtin_amdgcn_s_barrier();
      __builtin_amdgcn_sched_barrier(0);
    }
    if (kt + 2 < 12) stage(kt + 2);          // writes slot (kt+2)%3==(kt-1)%3:
                                             // its readers' MFMAs ran at kt-1,
                                             // before the barrier above
    const char* Ab = smem + (kt % 3) * 40960;
    const char* Bb = Ab + 32768;
    bf16x8 a[8], bfr[4];
#pragma unroll
    for (int i = 0; i < 8; ++i)
      a[i] = *(const bf16x8*)(Ab + (wr * 128 + i * 16 + l15) * 64 + slot * 16);
#pragma unroll
    for (int ni = 0; ni < 4; ++ni)
      bfr[ni] = *(const bf16x8*)(Bb + (wc * 64 + ni * 16 + l15) * 64 + slot * 16);
    __builtin_amdgcn_s_setprio(1);
#pragma unroll
    for (int mi = 0; mi < 8; ++mi)
#pragma unroll
      for (int ni = 0; ni < 4; ++ni)
        acc[mi][ni] = __builtin_amdgcn_mfma_f32_16x16x32_bf16(a[mi], bfr[ni],
                                                              acc[mi][ni], 0, 0, 0);
    __builtin_amdgcn_s_setprio(0);
    // tile kt+1 must land before next barrier; keep tile kt+2 (5) in flight
    if (kt <= 9)       asm volatile("s_waitcnt vmcnt(5)" ::: "memory");
    else if (kt == 10) asm volatile("s_waitcnt vmcnt(0)" ::: "memory");
    __builtin_amdgcn_sched_barrier(0);
  }

#pragma unroll
  for (int ni = 0; ni < 4; ++ni) {
    int chan = cb + wc * 64 + ni * 16 + l15;
    float bv_ = bias[chan];
#pragma unroll
    for (int mi = 0; mi < 8; ++mi)
#pragma unroll
      for (int r = 0; r < 4; ++r) {
        int row = m0 + wr * 128 + mi * 16 + hi * 4 + r;
        Out[(size_t)row * 384 + chan] = (bf16_t)(acc[mi][ni][r] + bv_);
      }
  }
}

// ---------------- attention: one wave per 2048-flat chunk ----------------
__global__ __launch_bounds__(64) void attn_kernel(const bf16_t* __restrict__ Q,
                                                  const bf16_t* __restrict__ K,
                                                  const bf16_t* __restrict__ V,
                                                  bf16_t* __restrict__ O) {
  const size_t base = (size_t)blockIdx.x * 2048;
  const bf16_t* q = Q + base;
  const bf16_t* k = K + base;
  const bf16_t* v = V + base;
  bf16_t* o = O + base;
  const int lane = threadIdx.x;
  const int l15 = lane & 15, hi = lane >> 4;

  __shared__ __align__(16) bf16_t Vt[32][72];  // V transposed [d][k]
  __shared__ __align__(16) bf16_t Ps[64][72];  // P (attn weights) [q][k]

#pragma unroll
  for (int j = 0; j < 4; ++j) {
    bf16x8 vv = *(const bf16x8*)(v + lane * 32 + j * 8);
#pragma unroll
    for (int e = 0; e < 8; ++e) Vt[j * 8 + e][lane] = vv[e];
  }

  bf16x8 aQ[4], bK[4];
#pragma unroll
  for (int i = 0; i < 4; ++i) {
    aQ[i] = *(const bf16x8*)(q + (i * 16 + l15) * 32 + hi * 8);
    bK[i] = *(const bf16x8*)(k + (i * 16 + l15) * 32 + hi * 8);
  }
  f32x4 sc[4][4] = {};
#pragma unroll
  for (int mi = 0; mi < 4; ++mi)
#pragma unroll
    for (int ni = 0; ni < 4; ++ni)
      sc[mi][ni] = __builtin_amdgcn_mfma_f32_16x16x32_bf16(aQ[mi], bK[ni],
                                                           sc[mi][ni], 0, 0, 0);

  const float SCALE = 0.17677669529663687f;  // 32^-0.5
  float rs[4][4];
#pragma unroll
  for (int mi = 0; mi < 4; ++mi) {
#pragma unroll
    for (int r = 0; r < 4; ++r) {
      float s0 = sc[mi][0][r] * SCALE, s1 = sc[mi][1][r] * SCALE;
      float s2 = sc[mi][2][r] * SCALE, s3 = sc[mi][3][r] * SCALE;
      float mx = fmaxf(fmaxf(s0, s1), fmaxf(s2, s3));
      mx = fmaxf(mx, __shfl_xor(mx, 1));
      mx = fmaxf(mx, __shfl_xor(mx, 2));
      mx = fmaxf(mx, __shfl_xor(mx, 4));
      mx = fmaxf(mx, __shfl_xor(mx, 8));
      float p0 = __expf(s0 - mx), p1 = __expf(s1 - mx);
      float p2 = __expf(s2 - mx), p3 = __expf(s3 - mx);
      int row = mi * 16 + hi * 4 + r;
      Ps[row][0 + l15] = (bf16_t)p0;
      Ps[row][16 + l15] = (bf16_t)p1;
      Ps[row][32 + l15] = (bf16_t)p2;
      Ps[row][48 + l15] = (bf16_t)p3;
      float sum = p0 + p1 + p2 + p3;
      sum += __shfl_xor(sum, 1);
      sum += __shfl_xor(sum, 2);
      sum += __shfl_xor(sum, 4);
      sum += __shfl_xor(sum, 8);
      rs[mi][r] = sum;
    }
  }
  __syncthreads();

  f32x4 oacc[4][2] = {};
#pragma unroll
  for (int mi = 0; mi < 4; ++mi)
#pragma unroll
    for (int ks = 0; ks < 2; ++ks) {
      bf16x8 aP = *(const bf16x8*)(&Ps[mi * 16 + l15][ks * 32 + hi * 8]);
#pragma unroll
      for (int n2 = 0; n2 < 2; ++n2) {
        bf16x8 bV = *(const bf16x8*)(&Vt[n2 * 16 + l15][ks * 32 + hi * 8]);
        oacc[mi][n2] = __builtin_amdgcn_mfma_f32_16x16x32_bf16(aP, bV,
                                                               oacc[mi][n2], 0, 0, 0);
      }
    }
#pragma unroll
  for (int mi = 0; mi < 4; ++mi)
#pragma unroll
    for (int n2 = 0; n2 < 2; ++n2)
#pragma unroll
      for (int r = 0; r < 4; ++r) {
        int row = mi * 16 + hi * 4 + r;
        o[row * 32 + n2 * 16 + l15] = (bf16_t)(oacc[mi][n2][r] / rs[mi][r]);
      }
}

// ---------------- generic 128x128 bf16 GEMM mainloop (proj) ----------------
__device__ __forceinline__ void stage_tile(const bf16_t* __restrict__ A,
                                           const bf16_t* __restrict__ B,
                                           bf16_t* As, bf16_t* Bs, int k0, int tid) {
  const int lane = tid & 63, wvv = tid >> 6;
  const int s = (lane & 3) ^ ((lane >> 3) & 3);
#pragma unroll
  for (int j = 0; j < 2; ++j) {
    int q = wvv * 128 + j * 64 + lane;
    int row = q >> 2;
    gload_lds16(A + (size_t)row * 384 + k0 + s * 8,
                (char*)As + (wvv * 128 + j * 64) * 16);
    gload_lds16(B + (size_t)row * 384 + k0 + s * 8,
                (char*)Bs + (wvv * 128 + j * 64) * 16);
  }
}

__device__ __forceinline__ void gemm_mainloop(const bf16_t* __restrict__ Arows,
                                              const bf16_t* __restrict__ Brows,
                                              bf16_t* As, bf16_t* Bs,
                                              int tid, f32x4 acc[4][4]) {
  const int lane = tid & 63;
  const int l15 = lane & 15, hi = lane >> 4;
  const int wr = (tid >> 6) >> 1, wc = (tid >> 6) & 1;
  const int slot = hi ^ ((l15 >> 1) & 3);
  stage_tile(Arows, Brows, As, Bs, 0, tid);
  stage_tile(Arows, Brows, As + 4096, Bs + 4096, 32, tid);
#pragma unroll
  for (int kt = 0; kt < 12; ++kt) {
    bf16_t* Ab = As + (kt & 1) * 4096;
    bf16_t* Bb = Bs + (kt & 1) * 4096;
    if (kt == 11) asm volatile("s_waitcnt vmcnt(0)" ::: "memory");
    else          asm volatile("s_waitcnt vmcnt(4)" ::: "memory");
    __builtin_amdgcn_s_barrier();
    bf16x8 a[4], bfr[4];
#pragma unroll
    for (int i = 0; i < 4; ++i) {
      a[i] = *(const bf16x8*)(Ab + (wr * 64 + i * 16 + l15) * 32 + slot * 8);
      bfr[i] = *(const bf16x8*)(Bb + (wc * 64 + i * 16 + l15) * 32 + slot * 8);
    }
#pragma unroll
    for (int mi = 0; mi < 4; ++mi)
#pragma unroll
      for (int ni = 0; ni < 4; ++ni)
        acc[mi][ni] = __builtin_amdgcn_mfma_f32_16x16x32_bf16(a[mi], bfr[ni],
                                                              acc[mi][ni], 0, 0, 0);
    asm volatile("s_waitcnt lgkmcnt(0)" ::: "memory");
    __builtin_amdgcn_sched_barrier(0);
    __builtin_amdgcn_s_barrier();
    if (kt + 2 < 12)
      stage_tile(Arows, Brows, Ab, Bb, (kt + 2) * 32, tid);
  }
}

// ---------------- output projection GEMM ----------------
__global__ __launch_bounds__(256) void proj_gemm(const bf16_t* __restrict__ Wpb,
                                                 const bf16_t* __restrict__ O,
                                                 const float* __restrict__ bp,
                                                 float* __restrict__ y) {
  __shared__ __align__(16) bf16_t As[2 * 128 * 32];
  __shared__ __align__(16) bf16_t Bs[2 * 128 * 32];
  const int tid = threadIdx.x;
  const int F = blockIdx.x;            // 1536 = 8 xcd * 3 j * 64 gq
  const int xcd = F & 7;
  const int t = F >> 3;
  const int j = t % 3;                 // out-chan tile
  const int gq = t / 3;
  const int g = gq * 8 + xcd;          // 0..511 -> (pix tile, batch)
  const int n0 = (g & 127) * 128;      // pixels within batch
  const int b = g >> 7;
  const int m0 = j * 128;              // out channels
  f32x4 acc[4][4] = {};
  gemm_mainloop(Wpb + (size_t)m0 * 384, O + ((size_t)b * 16384 + n0) * 384,
                As, Bs, tid, acc);
  const int lane = tid & 63, wvv = tid >> 6;
  const int l15 = lane & 15, hi = lane >> 4;
  const int wr = wvv >> 1, wc = wvv & 1;
  float* yb = y + (size_t)b * 6291456;
#pragma unroll
  for (int mi = 0; mi < 4; ++mi)
#pragma unroll
    for (int r = 0; r < 4; ++r) {
      int och = m0 + wr * 64 + mi * 16 + hi * 4 + r;
      float bpv = bp[och];
#pragma unroll
      for (int ni = 0; ni < 4; ++ni) {
        int pix = n0 + wc * 64 + ni * 16 + l15;
        yb[(size_t)och * 16384 + pix] = acc[mi][ni][r] + bpv;
      }
    }
}

extern "C" void kernel_launch(void* const* d_in, const int* in_sizes, int n_in,
                              void* d_out, int out_size, void* d_ws, size_t ws_size,
                              hipStream_t stream) {
  const float* x  = (const float*)d_in[0];
  const float* Wq = (const float*)d_in[1];
  const float* bq = (const float*)d_in[2];
  const float* Wk = (const float*)d_in[3];
  const float* bk = (const float*)d_in[4];
  const float* Wv = (const float*)d_in[5];
  const float* bv = (const float*)d_in[6];
  const float* Wp = (const float*)d_in[7];
  const float* bp = (const float*)d_in[8];
  float* y = (float*)d_out;

  char* ws = (char*)d_ws;
  const size_t SZ = 50331648;               // 65536*384*2 bytes
  bf16_t* Xp  = (bf16_t*)(ws);              // [65536][384]; reused as O later
  bf16_t* Vs  = (bf16_t*)(ws + SZ);
  bf16_t* Wcat = (bf16_t*)(ws + 2 * SZ);    // [1152][384] = Wq|Wk|Wv rows
  bf16_t* Wkb = Wcat + 147456;
  bf16_t* Wvb = Wkb + 147456;
  bf16_t* Wpb = Wvb + 147456;
  bf16_t* Qs  = (bf16_t*)d_out;             // stash Q,K in d_out (exact fit)
  bf16_t* Ks  = (bf16_t*)((char*)d_out + SZ);
  bf16_t* Ob  = Xp;

  hipFuncSetAttribute((const void*)qkv_gemm,
                      hipFuncAttributeMaxDynamicSharedMemorySize, 122880);

  convw_kernel<<<576, 256, 0, stream>>>(Wq, Wk, Wv, Wp, Wcat, Wkb, Wvb, Wpb);
  prep_kernel<<<24576, 256, 0, stream>>>(x, Xp);
  qkv_gemm<<<1152, 512, 122880, stream>>>(Xp, Wcat, bq, bk, bv, Qs, Ks, Vs);
  attn_kernel<<<12288, 64, 0, stream>>>(Qs, Ks, Vs, Ob);
  proj_gemm<<<1536, 256, 0, stream>>>(Wpb, Ob, bp, y);
}

// Round 11
// 187.280 us; speedup vs baseline: 1.0548x; 1.0548x over previous
//
#include <hip/hip_runtime.h>
#include <hip/hip_bf16.h>
#include <stdint.h>

// W-MSA on flat-reinterpreted windows.
// pp = n1<<10|n3<<6|w2<<3|w4  ->  P = n1<<10|w2<<7|n3<<3|w4
// QKV/proj are plain GEMMs on x.view(B*16384,384) in pp-row order; each
// attention (h,n') block is a contiguous 2048-element chunk of the FLAT
// [pp*384+c] Q/K/V arrays, viewed [64][32] row-major.
// qkv R11: BM=256, BN=128, 8 waves (4Mx2N, 64x64 wave-tile), 3-slot 24KB ring
// = 72KB LDS -> 2 blocks/CU (the R9/R10 120KB rings allowed only 1). Wall was
// latency/sync (post-barrier LDS-read serialization with no co-resident
// block); cross-block TLP is the lever, same ring discipline as R10.

typedef __bf16 bf16_t;
typedef __bf16 bf16x8 __attribute__((ext_vector_type(8)));
typedef __bf16 bf16x4 __attribute__((ext_vector_type(4)));
typedef float f32x4 __attribute__((ext_vector_type(4)));

__device__ __forceinline__ void gload_lds16(const void* g, void* l) {
  __builtin_amdgcn_global_load_lds((__attribute__((address_space(1))) void*)(g),
                                   (__attribute__((address_space(3))) void*)(l),
                                   16, 0, 0);
}

// ---------------- weight fp32->bf16 (Wq|Wk|Wv concatenated, then Wp) -------
__global__ __launch_bounds__(256) void convw_kernel(
    const float* __restrict__ wq, const float* __restrict__ wk,
    const float* __restrict__ wv, const float* __restrict__ wp,
    bf16_t* __restrict__ oq, bf16_t* __restrict__ ok,
    bf16_t* __restrict__ ov, bf16_t* __restrict__ op_) {
  int i = blockIdx.x * 256 + threadIdx.x;  // grid covers exactly 147456
  oq[i] = (bf16_t)wq[i];
  ok[i] = (bf16_t)wk[i];
  ov[i] = (bf16_t)wv[i];
  op_[i] = (bf16_t)wp[i];
}

// ---------------- prep: row-permute + cast ----------------
__global__ __launch_bounds__(256) void prep_kernel(const float* __restrict__ x,
                                                   bf16_t* __restrict__ Xp) {
  int gid = blockIdx.x * 256 + threadIdx.x;   // 65536 rows * 96 float4 chunks
  int row = gid / 96;
  int c4 = (gid - row * 96) * 4;
  int b = row >> 14;
  int pp = row & 16383;
  int n1 = pp >> 10, n3 = (pp >> 6) & 15, w2 = (pp >> 3) & 7, w4 = pp & 7;
  int P = (n1 << 10) | (w2 << 7) | (n3 << 3) | w4;
  float4 v = *(const float4*)(x + (size_t)((b << 14) | P) * 384 + c4);
  bf16x4 o;
  o[0] = (bf16_t)v.x; o[1] = (bf16_t)v.y; o[2] = (bf16_t)v.z; o[3] = (bf16_t)v.w;
  *(bf16x4*)(Xp + (size_t)row * 384 + c4) = o;
}

// ---------------- QKV GEMM: 3-slot ring, 2 blocks/CU ----------
// Slot (kt%3): A [256 rows][4 granules of 16B] 16KB | B [128][4] 8KB.
// Granule g of row r stored at position g^((r>>1)&3) via swizzled SOURCE
// address (linear glds dest); read position hi^((l15>>1)&3) (R2-verified).
__global__ __launch_bounds__(512, 4) void qkv_gemm(
    const bf16_t* __restrict__ Xp, const bf16_t* __restrict__ Wcat,
    const float* __restrict__ bq, const float* __restrict__ bk,
    const float* __restrict__ bv,
    bf16_t* __restrict__ Qs, bf16_t* __restrict__ Ks, bf16_t* __restrict__ Vs) {
  extern __shared__ __align__(16) char smem[];  // 3 * 24576 = 73728 B
  const int tid = threadIdx.x;
  const int F = blockIdx.x;            // 2304 = 8 xcd * 9 j * 32 gq
  const int xcd = F & 7;
  const int t = F >> 3;
  const int j = t % 9;                 // n-tile over 1152 out chans
  const int gq = t / 9;
  const int m0 = (gq * 8 + xcd) * 256; // pixel-row tile (256 rows)
  const int which = j / 3;
  const int cb = (j % 3) * 128;
  const float* bias = which == 0 ? bq : (which == 1 ? bk : bv);
  bf16_t* Out = which == 0 ? Qs : (which == 1 ? Ks : Vs);
  const bf16_t* Arows = Xp + (size_t)m0 * 384;
  const bf16_t* Brows = Wcat + (size_t)j * 128 * 384;

  const int lane = tid & 63, wid = tid >> 6;
  const int l15 = lane & 15, hi = lane >> 4;
  const int wr = wid >> 1, wc = wid & 1;     // 4M x 2N waves, 64x64 tiles
  const int slot = hi ^ ((l15 >> 1) & 3);    // swizzled read position

  auto stage = [&](int kt) {                 // 3 glds/thread
    const int k0 = kt * 32;
    char* base = smem + (kt % 3) * 24576;
#pragma unroll
    for (int jj = 0; jj < 2; ++jj) {         // A: 256 rows x 4 granules
      int idx = jj * 512 + tid;
      int row = idx >> 2;
      int sg = (idx & 3) ^ ((idx >> 3) & 3);
      gload_lds16(Arows + (size_t)row * 384 + k0 + sg * 8,
                  base + (jj * 512 + wid * 64) * 16);
    }
    {                                        // B: 128 rows x 4 granules
      int row = tid >> 2;
      int sg = (tid & 3) ^ ((tid >> 3) & 3);
      gload_lds16(Brows + (size_t)row * 384 + k0 + sg * 8,
                  base + 16384 + (wid * 64) * 16);
    }
  };

  stage(0); stage(1);
  // own tile-0 loads done before the barrier -> barrier publishes tile 0.
  asm volatile("s_waitcnt vmcnt(3)" ::: "memory");
  __builtin_amdgcn_s_barrier();
  __builtin_amdgcn_sched_barrier(0);

  f32x4 acc[4][4] = {};
#pragma unroll
  for (int kt = 0; kt < 12; ++kt) {
    if (kt > 0) {
      __builtin_amdgcn_s_barrier();
      __builtin_amdgcn_sched_barrier(0);
    }
    if (kt + 2 < 12) stage(kt + 2);          // writes slot (kt+2)%3==(kt-1)%3:
                                             // its ds_reads completed before
                                             // MFMA at kt-1 < barrier above
    const char* Ab = smem + (kt % 3) * 24576;
    const char* Bb = Ab + 16384;
    bf16x8 a[4], bfr[4];
#pragma unroll
    for (int i = 0; i < 4; ++i)
      a[i] = *(const bf16x8*)(Ab + (wr * 64 + i * 16 + l15) * 64 + slot * 16);
#pragma unroll
    for (int ni = 0; ni < 4; ++ni)
      bfr[ni] = *(const bf16x8*)(Bb + (wc * 64 + ni * 16 + l15) * 64 + slot * 16);
    __builtin_amdgcn_s_setprio(1);
#pragma unroll
    for (int mi = 0; mi < 4; ++mi)
#pragma unroll
      for (int ni = 0; ni < 4; ++ni)
        acc[mi][ni] = __builtin_amdgcn_mfma_f32_16x16x32_bf16(a[mi], bfr[ni],
                                                              acc[mi][ni], 0, 0, 0);
    __builtin_amdgcn_s_setprio(0);
    // tile kt+1 must land before next barrier; keep stage(kt+2) in flight
    if (kt <= 9)       asm volatile("s_waitcnt vmcnt(3)" ::: "memory");
    else if (kt == 10) asm volatile("s_waitcnt vmcnt(0)" ::: "memory");
    __builtin_amdgcn_sched_barrier(0);
  }

#pragma unroll
  for (int ni = 0; ni < 4; ++ni) {
    int chan = cb + wc * 64 + ni * 16 + l15;
    float bv_ = bias[chan];
#pragma unroll
    for (int mi = 0; mi < 4; ++mi)
#pragma unroll
      for (int r = 0; r < 4; ++r) {
        int row = m0 + wr * 64 + mi * 16 + hi * 4 + r;
        Out[(size_t)row * 384 + chan] = (bf16_t)(acc[mi][ni][r] + bv_);
      }
  }
}

// ---------------- attention: one wave per 2048-flat chunk ----------------
__global__ __launch_bounds__(64) void attn_kernel(const bf16_t* __restrict__ Q,
                                                  const bf16_t* __restrict__ K,
                                                  const bf16_t* __restrict__ V,
                                                  bf16_t* __restrict__ O) {
  const size_t base = (size_t)blockIdx.x * 2048;
  const bf16_t* q = Q + base;
  const bf16_t* k = K + base;
  const bf16_t* v = V + base;
  bf16_t* o = O + base;
  const int lane = threadIdx.x;
  const int l15 = lane & 15, hi = lane >> 4;

  __shared__ __align__(16) bf16_t Vt[32][72];  // V transposed [d][k]
  __shared__ __align__(16) bf16_t Ps[64][72];  // P (attn weights) [q][k]

#pragma unroll
  for (int j = 0; j < 4; ++j) {
    bf16x8 vv = *(const bf16x8*)(v + lane * 32 + j * 8);
#pragma unroll
    for (int e = 0; e < 8; ++e) Vt[j * 8 + e][lane] = vv[e];
  }

  bf16x8 aQ[4], bK[4];
#pragma unroll
  for (int i = 0; i < 4; ++i) {
    aQ[i] = *(const bf16x8*)(q + (i * 16 + l15) * 32 + hi * 8);
    bK[i] = *(const bf16x8*)(k + (i * 16 + l15) * 32 + hi * 8);
  }
  f32x4 sc[4][4] = {};
#pragma unroll
  for (int mi = 0; mi < 4; ++mi)
#pragma unroll
    for (int ni = 0; ni < 4; ++ni)
      sc[mi][ni] = __builtin_amdgcn_mfma_f32_16x16x32_bf16(aQ[mi], bK[ni],
                                                           sc[mi][ni], 0, 0, 0);

  const float SCALE = 0.17677669529663687f;  // 32^-0.5
  float rs[4][4];
#pragma unroll
  for (int mi = 0; mi < 4; ++mi) {
#pragma unroll
    for (int r = 0; r < 4; ++r) {
      float s0 = sc[mi][0][r] * SCALE, s1 = sc[mi][1][r] * SCALE;
      float s2 = sc[mi][2][r] * SCALE, s3 = sc[mi][3][r] * SCALE;
      float mx = fmaxf(fmaxf(s0, s1), fmaxf(s2, s3));
      mx = fmaxf(mx, __shfl_xor(mx, 1));
      mx = fmaxf(mx, __shfl_xor(mx, 2));
      mx = fmaxf(mx, __shfl_xor(mx, 4));
      mx = fmaxf(mx, __shfl_xor(mx, 8));
      float p0 = __expf(s0 - mx), p1 = __expf(s1 - mx);
      float p2 = __expf(s2 - mx), p3 = __expf(s3 - mx);
      int row = mi * 16 + hi * 4 + r;
      Ps[row][0 + l15] = (bf16_t)p0;
      Ps[row][16 + l15] = (bf16_t)p1;
      Ps[row][32 + l15] = (bf16_t)p2;
      Ps[row][48 + l15] = (bf16_t)p3;
      float sum = p0 + p1 + p2 + p3;
      sum += __shfl_xor(sum, 1);
      sum += __shfl_xor(sum, 2);
      sum += __shfl_xor(sum, 4);
      sum += __shfl_xor(sum, 8);
      rs[mi][r] = sum;
    }
  }
  __syncthreads();

  f32x4 oacc[4][2] = {};
#pragma unroll
  for (int mi = 0; mi < 4; ++mi)
#pragma unroll
    for (int ks = 0; ks < 2; ++ks) {
      bf16x8 aP = *(const bf16x8*)(&Ps[mi * 16 + l15][ks * 32 + hi * 8]);
#pragma unroll
      for (int n2 = 0; n2 < 2; ++n2) {
        bf16x8 bV = *(const bf16x8*)(&Vt[n2 * 16 + l15][ks * 32 + hi * 8]);
        oacc[mi][n2] = __builtin_amdgcn_mfma_f32_16x16x32_bf16(aP, bV,
                                                               oacc[mi][n2], 0, 0, 0);
      }
    }
#pragma unroll
  for (int mi = 0; mi < 4; ++mi)
#pragma unroll
    for (int n2 = 0; n2 < 2; ++n2)
#pragma unroll
      for (int r = 0; r < 4; ++r) {
        int row = mi * 16 + hi * 4 + r;
        o[row * 32 + n2 * 16 + l15] = (bf16_t)(oacc[mi][n2][r] / rs[mi][r]);
      }
}

// ---------------- generic 128x128 bf16 GEMM mainloop (proj) ----------------
__device__ __forceinline__ void stage_tile(const bf16_t* __restrict__ A,
                                           const bf16_t* __restrict__ B,
                                           bf16_t* As, bf16_t* Bs, int k0, int tid) {
  const int lane = tid & 63, wvv = tid >> 6;
  const int s = (lane & 3) ^ ((lane >> 3) & 3);
#pragma unroll
  for (int j = 0; j < 2; ++j) {
    int q = wvv * 128 + j * 64 + lane;
    int row = q >> 2;
    gload_lds16(A + (size_t)row * 384 + k0 + s * 8,
                (char*)As + (wvv * 128 + j * 64) * 16);
    gload_lds16(B + (size_t)row * 384 + k0 + s * 8,
                (char*)Bs + (wvv * 128 + j * 64) * 16);
  }
}

__device__ __forceinline__ void gemm_mainloop(const bf16_t* __restrict__ Arows,
                                              const bf16_t* __restrict__ Brows,
                                              bf16_t* As, bf16_t* Bs,
                                              int tid, f32x4 acc[4][4]) {
  const int lane = tid & 63;
  const int l15 = lane & 15, hi = lane >> 4;
  const int wr = (tid >> 6) >> 1, wc = (tid >> 6) & 1;
  const int slot = hi ^ ((l15 >> 1) & 3);
  stage_tile(Arows, Brows, As, Bs, 0, tid);
  stage_tile(Arows, Brows, As + 4096, Bs + 4096, 32, tid);
#pragma unroll
  for (int kt = 0; kt < 12; ++kt) {
    bf16_t* Ab = As + (kt & 1) * 4096;
    bf16_t* Bb = Bs + (kt & 1) * 4096;
    if (kt == 11) asm volatile("s_waitcnt vmcnt(0)" ::: "memory");
    else          asm volatile("s_waitcnt vmcnt(4)" ::: "memory");
    __builtin_amdgcn_s_barrier();
    bf16x8 a[4], bfr[4];
#pragma unroll
    for (int i = 0; i < 4; ++i) {
      a[i] = *(const bf16x8*)(Ab + (wr * 64 + i * 16 + l15) * 32 + slot * 8);
      bfr[i] = *(const bf16x8*)(Bb + (wc * 64 + i * 16 + l15) * 32 + slot * 8);
    }
#pragma unroll
    for (int mi = 0; mi < 4; ++mi)
#pragma unroll
      for (int ni = 0; ni < 4; ++ni)
        acc[mi][ni] = __builtin_amdgcn_mfma_f32_16x16x32_bf16(a[mi], bfr[ni],
                                                              acc[mi][ni], 0, 0, 0);
    asm volatile("s_waitcnt lgkmcnt(0)" ::: "memory");
    __builtin_amdgcn_sched_barrier(0);
    __builtin_amdgcn_s_barrier();
    if (kt + 2 < 12)
      stage_tile(Arows, Brows, Ab, Bb, (kt + 2) * 32, tid);
  }
}

// ---------------- output projection GEMM ----------------
__global__ __launch_bounds__(256) void proj_gemm(const bf16_t* __restrict__ Wpb,
                                                 const bf16_t* __restrict__ O,
                                                 const float* __restrict__ bp,
                                                 float* __restrict__ y) {
  __shared__ __align__(16) bf16_t As[2 * 128 * 32];
  __shared__ __align__(16) bf16_t Bs[2 * 128 * 32];
  const int tid = threadIdx.x;
  const int F = blockIdx.x;            // 1536 = 8 xcd * 3 j * 64 gq
  const int xcd = F & 7;
  const int t = F >> 3;
  const int j = t % 3;                 // out-chan tile
  const int gq = t / 3;
  const int g = gq * 8 + xcd;          // 0..511 -> (pix tile, batch)
  const int n0 = (g & 127) * 128;      // pixels within batch
  const int b = g >> 7;
  const int m0 = j * 128;              // out channels
  f32x4 acc[4][4] = {};
  gemm_mainloop(Wpb + (size_t)m0 * 384, O + ((size_t)b * 16384 + n0) * 384,
                As, Bs, tid, acc);
  const int lane = tid & 63, wvv = tid >> 6;
  const int l15 = lane & 15, hi = lane >> 4;
  const int wr = wvv >> 1, wc = wvv & 1;
  float* yb = y + (size_t)b * 6291456;
#pragma unroll
  for (int mi = 0; mi < 4; ++mi)
#pragma unroll
    for (int r = 0; r < 4; ++r) {
      int och = m0 + wr * 64 + mi * 16 + hi * 4 + r;
      float bpv = bp[och];
#pragma unroll
      for (int ni = 0; ni < 4; ++ni) {
        int pix = n0 + wc * 64 + ni * 16 + l15;
        yb[(size_t)och * 16384 + pix] = acc[mi][ni][r] + bpv;
      }
    }
}

extern "C" void kernel_launch(void* const* d_in, const int* in_sizes, int n_in,
                              void* d_out, int out_size, void* d_ws, size_t ws_size,
                              hipStream_t stream) {
  const float* x  = (const float*)d_in[0];
  const float* Wq = (const float*)d_in[1];
  const float* bq = (const float*)d_in[2];
  const float* Wk = (const float*)d_in[3];
  const float* bk = (const float*)d_in[4];
  const float* Wv = (const float*)d_in[5];
  const float* bv = (const float*)d_in[6];
  const float* Wp = (const float*)d_in[7];
  const float* bp = (const float*)d_in[8];
  float* y = (float*)d_out;

  char* ws = (char*)d_ws;
  const size_t SZ = 50331648;               // 65536*384*2 bytes
  bf16_t* Xp  = (bf16_t*)(ws);              // [65536][384]; reused as O later
  bf16_t* Vs  = (bf16_t*)(ws + SZ);
  bf16_t* Wcat = (bf16_t*)(ws + 2 * SZ);    // [1152][384] = Wq|Wk|Wv rows
  bf16_t* Wkb = Wcat + 147456;
  bf16_t* Wvb = Wkb + 147456;
  bf16_t* Wpb = Wvb + 147456;
  bf16_t* Qs  = (bf16_t*)d_out;             // stash Q,K in d_out (exact fit)
  bf16_t* Ks  = (bf16_t*)((char*)d_out + SZ);
  bf16_t* Ob  = Xp;

  hipFuncSetAttribute((const void*)qkv_gemm,
                      hipFuncAttributeMaxDynamicSharedMemorySize, 73728);

  convw_kernel<<<576, 256, 0, stream>>>(Wq, Wk, Wv, Wp, Wcat, Wkb, Wvb, Wpb);
  prep_kernel<<<24576, 256, 0, stream>>>(x, Xp);
  qkv_gemm<<<2304, 512, 73728, stream>>>(Xp, Wcat, bq, bk, bv, Qs, Ks, Vs);
  attn_kernel<<<12288, 64, 0, stream>>>(Qs, Ks, Vs, Ob);
  proj_gemm<<<1536, 256, 0, stream>>>(Wpb, Ob, bp, y);
}

// Round 12
// 182.625 us; speedup vs baseline: 1.0816x; 1.0255x over previous
//
#include <hip/hip_runtime.h>
#include <hip/hip_bf16.h>
#include <stdint.h>

// W-MSA on flat-reinterpreted windows.
// pp = n1<<10|n3<<6|w2<<3|w4  ->  P = n1<<10|w2<<7|n3<<3|w4
// QKV/proj are plain GEMMs on x.view(B*16384,384) in pp-row order; each
// attention (h,n') block is a contiguous 2048-element chunk of the FLAT
// [pp*384+c] Q/K/V arrays, viewed [64][32] row-major.
// R12: both GEMMs use BM=128,BN=128, 8 waves (2Mx4N, 64x32 wave-tile,
// acc[4][2]=32), 3-slot 16KB ring = 48KB LDS -> 3 blocks/CU, 6 waves/SIMD
// (launch_bounds(512,6)). R11 showed latency/TLP is the wall; this trades
// nothing but acc size for +50% occupancy. Counted vmcnt(2) ring as R11.

typedef __bf16 bf16_t;
typedef __bf16 bf16x8 __attribute__((ext_vector_type(8)));
typedef __bf16 bf16x4 __attribute__((ext_vector_type(4)));
typedef float f32x4 __attribute__((ext_vector_type(4)));

__device__ __forceinline__ void gload_lds16(const void* g, void* l) {
  __builtin_amdgcn_global_load_lds((__attribute__((address_space(1))) void*)(g),
                                   (__attribute__((address_space(3))) void*)(l),
                                   16, 0, 0);
}

// ---------------- fused weight-cast + prep (row-permute + cast) ----------
__global__ __launch_bounds__(256) void prepw_kernel(
    const float* __restrict__ x, bf16_t* __restrict__ Xp,
    const float* __restrict__ wq, const float* __restrict__ wk,
    const float* __restrict__ wv, const float* __restrict__ wp,
    bf16_t* __restrict__ oq, bf16_t* __restrict__ ok,
    bf16_t* __restrict__ ov, bf16_t* __restrict__ op_) {
  if (blockIdx.x < 576) {            // weights: 576*256 = 147456 exactly
    int i = blockIdx.x * 256 + threadIdx.x;
    oq[i] = (bf16_t)wq[i];
    ok[i] = (bf16_t)wk[i];
    ov[i] = (bf16_t)wv[i];
    op_[i] = (bf16_t)wp[i];
    return;
  }
  int gid = (blockIdx.x - 576) * 256 + threadIdx.x;  // 65536 rows * 96 chunks
  int row = gid / 96;
  int c4 = (gid - row * 96) * 4;
  int b = row >> 14;
  int pp = row & 16383;
  int n1 = pp >> 10, n3 = (pp >> 6) & 15, w2 = (pp >> 3) & 7, w4 = pp & 7;
  int P = (n1 << 10) | (w2 << 7) | (n3 << 3) | w4;
  float4 v = *(const float4*)(x + (size_t)((b << 14) | P) * 384 + c4);
  bf16x4 o;
  o[0] = (bf16_t)v.x; o[1] = (bf16_t)v.y; o[2] = (bf16_t)v.z; o[3] = (bf16_t)v.w;
  *(bf16x4*)(Xp + (size_t)row * 384 + c4) = o;
}

// ---------------- QKV GEMM: 3-slot ring, 3 blocks/CU, 6 waves/SIMD --------
// Slot (kt%3): A [128 rows][4 pos of 16B] 8KB | B [128][4] 8KB.
// Granule g of row r stored at position g^((r>>1)&3) via swizzled SOURCE
// address (linear glds dest); read position hi^((l15>>1)&3) (R2-verified).
__global__ __launch_bounds__(512, 6) void qkv_gemm(
    const bf16_t* __restrict__ Xp, const bf16_t* __restrict__ Wcat,
    const float* __restrict__ bq, const float* __restrict__ bk,
    const float* __restrict__ bv,
    bf16_t* __restrict__ Qs, bf16_t* __restrict__ Ks, bf16_t* __restrict__ Vs) {
  extern __shared__ __align__(16) char smem[];  // 3 * 16384 = 49152 B
  const int tid = threadIdx.x;
  const int F = blockIdx.x;            // 4608 = 8 xcd * 9 j * 64 gq
  const int xcd = F & 7;
  const int t = F >> 3;
  const int j = t % 9;                 // n-tile over 1152 out chans
  const int gq = t / 9;
  const int m0 = (gq * 8 + xcd) * 128; // pixel-row tile (128 rows)
  const int which = j / 3;
  const int cb = (j % 3) * 128;
  const float* bias = which == 0 ? bq : (which == 1 ? bk : bv);
  bf16_t* Out = which == 0 ? Qs : (which == 1 ? Ks : Vs);
  const bf16_t* Arows = Xp + (size_t)m0 * 384;
  const bf16_t* Brows = Wcat + (size_t)j * 128 * 384;

  const int lane = tid & 63, wid = tid >> 6;
  const int l15 = lane & 15, hi = lane >> 4;
  const int wr = wid >> 2, wc = wid & 3;     // 2M x 4N waves, 64x32 tiles
  const int slot = hi ^ ((l15 >> 1) & 3);    // swizzled read position

  auto stage = [&](int kt) {                 // 2 glds/thread
    const int k0 = kt * 32;
    char* base = smem + (kt % 3) * 16384;
    {                                        // A: 128 rows x 4 positions
      int row = tid >> 2;
      int sg = (tid & 3) ^ ((tid >> 3) & 3);
      gload_lds16(Arows + (size_t)row * 384 + k0 + sg * 8,
                  base + (wid * 64) * 16);
    }
    {                                        // B: 128 rows x 4 positions
      int row = tid >> 2;
      int sg = (tid & 3) ^ ((tid >> 3) & 3);
      gload_lds16(Brows + (size_t)row * 384 + k0 + sg * 8,
                  base + 8192 + (wid * 64) * 16);
    }
  };

  stage(0); stage(1);
  // own tile-0 loads done before the barrier -> barrier publishes tile 0.
  asm volatile("s_waitcnt vmcnt(2)" ::: "memory");
  __builtin_amdgcn_s_barrier();
  __builtin_amdgcn_sched_barrier(0);

  f32x4 acc[4][2] = {};
#pragma unroll
  for (int kt = 0; kt < 12; ++kt) {
    if (kt > 0) {
      __builtin_amdgcn_s_barrier();
      __builtin_amdgcn_sched_barrier(0);
    }
    if (kt + 2 < 12) stage(kt + 2);          // slot (kt+2)%3 == (kt-1)%3: its
                                             // readers' MFMAs ran at kt-1,
                                             // before the barrier above
    const char* Ab = smem + (kt % 3) * 16384;
    const char* Bb = Ab + 8192;
    bf16x8 a[4], bfr[2];
#pragma unroll
    for (int i = 0; i < 4; ++i)
      a[i] = *(const bf16x8*)(Ab + (wr * 64 + i * 16 + l15) * 64 + slot * 16);
#pragma unroll
    for (int ni = 0; ni < 2; ++ni)
      bfr[ni] = *(const bf16x8*)(Bb + (wc * 32 + ni * 16 + l15) * 64 + slot * 16);
    __builtin_amdgcn_s_setprio(1);
#pragma unroll
    for (int mi = 0; mi < 4; ++mi)
#pragma unroll
      for (int ni = 0; ni < 2; ++ni)
        acc[mi][ni] = __builtin_amdgcn_mfma_f32_16x16x32_bf16(a[mi], bfr[ni],
                                                              acc[mi][ni], 0, 0, 0);
    __builtin_amdgcn_s_setprio(0);
    // tile kt+1 must land before next barrier; keep stage(kt+2) in flight
    if (kt <= 9)       asm volatile("s_waitcnt vmcnt(2)" ::: "memory");
    else if (kt == 10) asm volatile("s_waitcnt vmcnt(0)" ::: "memory");
    __builtin_amdgcn_sched_barrier(0);
  }

#pragma unroll
  for (int ni = 0; ni < 2; ++ni) {
    int chan = cb + wc * 32 + ni * 16 + l15;
    float bv_ = bias[chan];
#pragma unroll
    for (int mi = 0; mi < 4; ++mi)
#pragma unroll
      for (int r = 0; r < 4; ++r) {
        int row = m0 + wr * 64 + mi * 16 + hi * 4 + r;
        Out[(size_t)row * 384 + chan] = (bf16_t)(acc[mi][ni][r] + bv_);
      }
  }
}

// ---------------- attention: one wave per 2048-flat chunk ----------------
__global__ __launch_bounds__(64) void attn_kernel(const bf16_t* __restrict__ Q,
                                                  const bf16_t* __restrict__ K,
                                                  const bf16_t* __restrict__ V,
                                                  bf16_t* __restrict__ O) {
  const size_t base = (size_t)blockIdx.x * 2048;
  const bf16_t* q = Q + base;
  const bf16_t* k = K + base;
  const bf16_t* v = V + base;
  bf16_t* o = O + base;
  const int lane = threadIdx.x;
  const int l15 = lane & 15, hi = lane >> 4;

  __shared__ __align__(16) bf16_t Vt[32][72];  // V transposed [d][k]
  __shared__ __align__(16) bf16_t Ps[64][72];  // P (attn weights) [q][k]

#pragma unroll
  for (int j = 0; j < 4; ++j) {
    bf16x8 vv = *(const bf16x8*)(v + lane * 32 + j * 8);
#pragma unroll
    for (int e = 0; e < 8; ++e) Vt[j * 8 + e][lane] = vv[e];
  }

  bf16x8 aQ[4], bK[4];
#pragma unroll
  for (int i = 0; i < 4; ++i) {
    aQ[i] = *(const bf16x8*)(q + (i * 16 + l15) * 32 + hi * 8);
    bK[i] = *(const bf16x8*)(k + (i * 16 + l15) * 32 + hi * 8);
  }
  f32x4 sc[4][4] = {};
#pragma unroll
  for (int mi = 0; mi < 4; ++mi)
#pragma unroll
    for (int ni = 0; ni < 4; ++ni)
      sc[mi][ni] = __builtin_amdgcn_mfma_f32_16x16x32_bf16(aQ[mi], bK[ni],
                                                           sc[mi][ni], 0, 0, 0);

  const float SCALE = 0.17677669529663687f;  // 32^-0.5
  float rs[4][4];
#pragma unroll
  for (int mi = 0; mi < 4; ++mi) {
#pragma unroll
    for (int r = 0; r < 4; ++r) {
      float s0 = sc[mi][0][r] * SCALE, s1 = sc[mi][1][r] * SCALE;
      float s2 = sc[mi][2][r] * SCALE, s3 = sc[mi][3][r] * SCALE;
      float mx = fmaxf(fmaxf(s0, s1), fmaxf(s2, s3));
      mx = fmaxf(mx, __shfl_xor(mx, 1));
      mx = fmaxf(mx, __shfl_xor(mx, 2));
      mx = fmaxf(mx, __shfl_xor(mx, 4));
      mx = fmaxf(mx, __shfl_xor(mx, 8));
      float p0 = __expf(s0 - mx), p1 = __expf(s1 - mx);
      float p2 = __expf(s2 - mx), p3 = __expf(s3 - mx);
      int row = mi * 16 + hi * 4 + r;
      Ps[row][0 + l15] = (bf16_t)p0;
      Ps[row][16 + l15] = (bf16_t)p1;
      Ps[row][32 + l15] = (bf16_t)p2;
      Ps[row][48 + l15] = (bf16_t)p3;
      float sum = p0 + p1 + p2 + p3;
      sum += __shfl_xor(sum, 1);
      sum += __shfl_xor(sum, 2);
      sum += __shfl_xor(sum, 4);
      sum += __shfl_xor(sum, 8);
      rs[mi][r] = sum;
    }
  }
  __syncthreads();

  f32x4 oacc[4][2] = {};
#pragma unroll
  for (int mi = 0; mi < 4; ++mi)
#pragma unroll
    for (int ks = 0; ks < 2; ++ks) {
      bf16x8 aP = *(const bf16x8*)(&Ps[mi * 16 + l15][ks * 32 + hi * 8]);
#pragma unroll
      for (int n2 = 0; n2 < 2; ++n2) {
        bf16x8 bV = *(const bf16x8*)(&Vt[n2 * 16 + l15][ks * 32 + hi * 8]);
        oacc[mi][n2] = __builtin_amdgcn_mfma_f32_16x16x32_bf16(aP, bV,
                                                               oacc[mi][n2], 0, 0, 0);
      }
    }
#pragma unroll
  for (int mi = 0; mi < 4; ++mi)
#pragma unroll
    for (int n2 = 0; n2 < 2; ++n2)
#pragma unroll
      for (int r = 0; r < 4; ++r) {
        int row = mi * 16 + hi * 4 + r;
        o[row * 32 + n2 * 16 + l15] = (bf16_t)(oacc[mi][n2][r] / rs[mi][r]);
      }
}

// ---------------- output projection: same ring structure ----------------
// A = Wp rows (och), B = O rows (pix); C[och][pix] -> coalesced fp32 y.
__global__ __launch_bounds__(512, 6) void proj_gemm(
    const bf16_t* __restrict__ Wpb, const bf16_t* __restrict__ O,
    const float* __restrict__ bp, float* __restrict__ y) {
  extern __shared__ __align__(16) char smem[];  // 3 * 16384 = 49152 B
  const int tid = threadIdx.x;
  const int F = blockIdx.x;            // 1536 = 8 xcd * 3 j * 64 gq
  const int xcd = F & 7;
  const int t = F >> 3;
  const int j = t % 3;                 // out-chan tile
  const int gq = t / 3;
  const int g = gq * 8 + xcd;          // 0..511 -> (pix tile, batch)
  const int n0 = (g & 127) * 128;      // pixels within batch
  const int b = g >> 7;
  const int m0 = j * 128;              // out channels
  const bf16_t* Arows = Wpb + (size_t)m0 * 384;
  const bf16_t* Brows = O + ((size_t)b * 16384 + n0) * 384;

  const int lane = tid & 63, wid = tid >> 6;
  const int l15 = lane & 15, hi = lane >> 4;
  const int wr = wid >> 2, wc = wid & 3;     // 2M x 4N waves, 64x32 tiles
  const int slot = hi ^ ((l15 >> 1) & 3);

  auto stage = [&](int kt) {                 // 2 glds/thread
    const int k0 = kt * 32;
    char* base = smem + (kt % 3) * 16384;
    int row = tid >> 2;
    int sg = (tid & 3) ^ ((tid >> 3) & 3);
    gload_lds16(Arows + (size_t)row * 384 + k0 + sg * 8,
                base + (wid * 64) * 16);
    gload_lds16(Brows + (size_t)row * 384 + k0 + sg * 8,
                base + 8192 + (wid * 64) * 16);
  };

  stage(0); stage(1);
  asm volatile("s_waitcnt vmcnt(2)" ::: "memory");
  __builtin_amdgcn_s_barrier();
  __builtin_amdgcn_sched_barrier(0);

  f32x4 acc[4][2] = {};
#pragma unroll
  for (int kt = 0; kt < 12; ++kt) {
    if (kt > 0) {
      __builtin_amdgcn_s_barrier();
      __builtin_amdgcn_sched_barrier(0);
    }
    if (kt + 2 < 12) stage(kt + 2);
    const char* Ab = smem + (kt % 3) * 16384;
    const char* Bb = Ab + 8192;
    bf16x8 a[4], bfr[2];
#pragma unroll
    for (int i = 0; i < 4; ++i)
      a[i] = *(const bf16x8*)(Ab + (wr * 64 + i * 16 + l15) * 64 + slot * 16);
#pragma unroll
    for (int ni = 0; ni < 2; ++ni)
      bfr[ni] = *(const bf16x8*)(Bb + (wc * 32 + ni * 16 + l15) * 64 + slot * 16);
    __builtin_amdgcn_s_setprio(1);
#pragma unroll
    for (int mi = 0; mi < 4; ++mi)
#pragma unroll
      for (int ni = 0; ni < 2; ++ni)
        acc[mi][ni] = __builtin_amdgcn_mfma_f32_16x16x32_bf16(a[mi], bfr[ni],
                                                              acc[mi][ni], 0, 0, 0);
    __builtin_amdgcn_s_setprio(0);
    if (kt <= 9)       asm volatile("s_waitcnt vmcnt(2)" ::: "memory");
    else if (kt == 10) asm volatile("s_waitcnt vmcnt(0)" ::: "memory");
    __builtin_amdgcn_sched_barrier(0);
  }

  float* yb = y + (size_t)b * 6291456;
#pragma unroll
  for (int mi = 0; mi < 4; ++mi)
#pragma unroll
    for (int r = 0; r < 4; ++r) {
      int och = m0 + wr * 64 + mi * 16 + hi * 4 + r;
      float bpv = bp[och];
#pragma unroll
      for (int ni = 0; ni < 2; ++ni) {
        int pix = n0 + wc * 32 + ni * 16 + l15;
        yb[(size_t)och * 16384 + pix] = acc[mi][ni][r] + bpv;
      }
    }
}

extern "C" void kernel_launch(void* const* d_in, const int* in_sizes, int n_in,
                              void* d_out, int out_size, void* d_ws, size_t ws_size,
                              hipStream_t stream) {
  const float* x  = (const float*)d_in[0];
  const float* Wq = (const float*)d_in[1];
  const float* bq = (const float*)d_in[2];
  const float* Wk = (const float*)d_in[3];
  const float* bk = (const float*)d_in[4];
  const float* Wv = (const float*)d_in[5];
  const float* bv = (const float*)d_in[6];
  const float* Wp = (const float*)d_in[7];
  const float* bp = (const float*)d_in[8];
  float* y = (float*)d_out;

  char* ws = (char*)d_ws;
  const size_t SZ = 50331648;               // 65536*384*2 bytes
  bf16_t* Xp  = (bf16_t*)(ws);              // [65536][384]; reused as O later
  bf16_t* Vs  = (bf16_t*)(ws + SZ);
  bf16_t* Wcat = (bf16_t*)(ws + 2 * SZ);    // [1152][384] = Wq|Wk|Wv rows
  bf16_t* Wkb = Wcat + 147456;
  bf16_t* Wvb = Wkb + 147456;
  bf16_t* Wpb = Wvb + 147456;
  bf16_t* Qs  = (bf16_t*)d_out;             // stash Q,K in d_out (exact fit)
  bf16_t* Ks  = (bf16_t*)((char*)d_out + SZ);
  bf16_t* Ob  = Xp;

  prepw_kernel<<<25152, 256, 0, stream>>>(x, Xp, Wq, Wk, Wv, Wp,
                                          Wcat, Wkb, Wvb, Wpb);
  qkv_gemm<<<4608, 512, 49152, stream>>>(Xp, Wcat, bq, bk, bv, Qs, Ks, Vs);
  attn_kernel<<<12288, 64, 0, stream>>>(Qs, Ks, Vs, Ob);
  proj_gemm<<<1536, 512, 49152, stream>>>(Wpb, Ob, bp, y);
}